// Round 3
// baseline (107.780 us; speedup 1.0000x reference)
//
#include <hip/hip_runtime.h>
#include <hip/hip_bf16.h>

typedef __attribute__((ext_vector_type(8))) short bf16x8;
typedef __attribute__((ext_vector_type(4))) float f32x4;
typedef __attribute__((ext_vector_type(4))) unsigned short u16x4;
typedef __attribute__((ext_vector_type(4))) unsigned int u32x4;

#define MFMA16(a, b, c) __builtin_amdgcn_mfma_f32_16x16x32_bf16((a), (b), (c), 0, 0, 0)

#define WQT_ELEMS 27648   // 288*96
#define WPT_ELEMS 9216    // 96*96

__device__ __forceinline__ unsigned short cvt_bf(float f) {
    __hip_bfloat16 h = __float2bfloat16(f);   // native RNE conversion
    return *reinterpret_cast<unsigned short*>(&h);
}
__device__ __forceinline__ unsigned pack2bf(float a, float b) {
    return (unsigned)cvt_bf(a) | ((unsigned)cvt_bf(b) << 16);
}

// Transpose+convert weights; q-columns (j<96) pre-scaled by (1/sqrt(24))*log2(e)
__global__ void wconv_kernel(const float* __restrict__ wqkv,
                             const float* __restrict__ wproj,
                             unsigned short* __restrict__ wsT) {
    int o = blockIdx.x * 256 + threadIdx.x;
    if (o < WQT_ELEMS) {
        int j = o / 96, c = o % 96;
        float w = wqkv[c * 288 + j];
        if (j < 96) w *= 0.2944889313f;
        wsT[o] = cvt_bf(w);
    } else if (o < WQT_ELEMS + WPT_ELEMS) {
        int o2 = o - WQT_ELEMS;
        int j = o2 / 96, c = o2 % 96;
        wsT[o] = cvt_bf(wproj[c * 96 + j]);
    }
}

// Packed-swizzled address for the unified x/q/O buffer: logical (t in [0,64), c in [0,96)).
// 3 chunks of 32 cols; 2 token-rows per 128B line; XOR swizzle on bits 4-6.
// All bf16x8 reads are <=2-way bank conflicted (free).
__device__ __forceinline__ int xq_addr(int t, int c) {
    return ((c >> 5) << 12) + ((t >> 1) << 7)
         + ((((t & 1) << 6) + ((c & 31) << 1)) ^ (((t >> 1) & 7) << 4));
}

// One block per window. 256 threads = 4 waves. Wave wv owns token rows [16wv,16wv+16).
// LDS = 40960 B exactly -> 4 blocks/CU; VGPR capped 128 by launch_bounds.
__global__ __launch_bounds__(256, 4)
void winattn_kernel(const float* __restrict__ x,
                    const unsigned short* __restrict__ wsT,
                    const float* __restrict__ bproj,
                    float* __restrict__ out) {
    __shared__ __align__(16) char xq[12288];    // x -> q -> O (packed-swizzled)
    __shared__ __align__(16) char ksb[16384];   // k [t][hd*32+kk], XOR-swizzled, kk 24..31 zero
    __shared__ __align__(16) char vtb[12288];   // v^T [c][t], XOR-swizzled

    const int tid = threadIdx.x;
    const int lane = tid & 63;
    const int wv = tid >> 6;
    const int p  = lane & 15;
    const int qg = lane >> 4;

    const int iw  = blockIdx.x;
    const int l_i = iw & 31;
    const int m_i = (iw >> 5) & 15;
    const int n_i = iw >> 9;

    const f32x4 fzero = {0.f, 0.f, 0.f, 0.f};

    // ---------- phase 1: stage x window -> LDS (bf16, packed layout) ----------
    #pragma unroll
    for (int it = 0; it < 6; ++it) {
        int slot = tid + it * 256;            // 64 tokens * 24 float4 slots
        int t = slot / 24, cq = slot % 24;
        int td = t >> 4, th = (t >> 2) & 3, tw = t & 3;
        int off = (((n_i * 4 + td) * 64 + (m_i * 4 + th)) * 128 + (l_i * 4 + tw)) * 96 + cq * 4;
        float4 v4 = *reinterpret_cast<const float4*>(x + off);
        u16x4 h;
        h[0] = cvt_bf(v4.x); h[1] = cvt_bf(v4.y); h[2] = cvt_bf(v4.z); h[3] = cvt_bf(v4.w);
        *reinterpret_cast<u16x4*>(xq + xq_addr(t, cq * 4)) = h;
    }
    // zero k head-pads (kk 24..31 per head, swizzled addr)
    {
        int t = tid >> 2, hd = tid & 3;
        bf16x8 z = {0, 0, 0, 0, 0, 0, 0, 0};
        int cb = hd * 64 + 48;
        *reinterpret_cast<bf16x8*>(ksb + t * 256 + (cb ^ ((t & 7) << 4))) = z;
    }
    __syncthreads();

    // ---------- phase 2: QKV GEMM  qkv[64][288] = x[64][96] @ wq[96][288] ----------
    bf16x8 afr[4][3];
    #pragma unroll
    for (int mt = 0; mt < 4; ++mt)
        #pragma unroll
        for (int kt = 0; kt < 3; ++kt)
            afr[mt][kt] = *reinterpret_cast<const bf16x8*>(xq + xq_addr(mt * 16 + p, kt * 32 + qg * 8));
    __syncthreads();   // xq fully register-hoisted; q may now overwrite it

    auto do_tile = [&](int nt) {
        f32x4 acc[4] = {fzero, fzero, fzero, fzero};
        #pragma unroll
        for (int kt = 0; kt < 3; ++kt) {
            bf16x8 bfr = *reinterpret_cast<const bf16x8*>(&wsT[(nt * 16 + p) * 96 + kt * 32 + qg * 8]);
            #pragma unroll
            for (int mt = 0; mt < 4; ++mt)
                acc[mt] = MFMA16(afr[mt][kt], bfr, acc[mt]);
        }
        int jcol = nt * 16 + p;               // D: col = lane&15, row = qg*4+rg (+16mt)
        if (jcol < 96) {                      // q (pre-scaled via weights)
            #pragma unroll
            for (int mt = 0; mt < 4; ++mt)
                #pragma unroll
                for (int rg = 0; rg < 4; ++rg)
                    *reinterpret_cast<unsigned short*>(xq + xq_addr(mt * 16 + qg * 4 + rg, jcol)) = cvt_bf(acc[mt][rg]);
        } else if (jcol < 192) {              // k, swizzled
            int jk = jcol - 96;
            int hd = jk / 24, kk = jk % 24;
            int cb = hd * 64 + kk * 2;
            #pragma unroll
            for (int mt = 0; mt < 4; ++mt)
                #pragma unroll
                for (int rg = 0; rg < 4; ++rg) {
                    int t = mt * 16 + qg * 4 + rg;
                    *reinterpret_cast<unsigned short*>(ksb + t * 256 + (cb ^ ((t & 7) << 4))) = cvt_bf(acc[mt][rg]);
                }
        } else {                              // v^T, swizzled
            int jv = jcol - 192;
            int hd = jv / 24, cc = jv % 24;
            int vr = hd * 24 + cc;
            int rb = vr * 128, sw = (vr & 7) << 4;
            #pragma unroll
            for (int mt = 0; mt < 4; ++mt)
                #pragma unroll
                for (int rg = 0; rg < 4; ++rg) {
                    int u = mt * 16 + qg * 4 + rg;
                    *reinterpret_cast<unsigned short*>(vtb + rb + ((u * 2) ^ sw)) = cvt_bf(acc[mt][rg]);
                }
        }
    };
    // tiles: wv0: 0-4, wv1: 5-9, wv2: 10-13, wv3: 14-17
    int base = (wv < 2) ? wv * 5 : 10 + (wv - 2) * 4;
    #pragma unroll
    for (int i = 0; i < 4; ++i) do_tile(base + i);
    if (wv < 2) do_tile(base + 4);
    __syncthreads();

    // ---------- phase 3: attention, swapped QK^T -> register softmax ----------
    #pragma unroll 1
    for (int hd = 0; hd < 4; ++hd) {
        // S^T = mfma(K, Q): D[col=q-token(p), row=k-token(qg*4+rg)+16nt]
        bf16x8 aqh = *reinterpret_cast<const bf16x8*>(xq + xq_addr(wv * 16 + p, hd * 24 + qg * 8));
        f32x4 sacc[4];
        #pragma unroll
        for (int nt = 0; nt < 4; ++nt) {
            int t = nt * 16 + p;
            bf16x8 ak = *reinterpret_cast<const bf16x8*>(ksb + t * 256 + ((hd * 64 + qg * 16) ^ ((t & 7) << 4)));
            sacc[nt] = MFMA16(ak, aqh, fzero);
        }
        // lane (p,qg) holds S[k = 16nt+4qg+rg][q = wv*16+p] (already *scale*log2e)
        float mm = sacc[0][0];
        #pragma unroll
        for (int nt = 0; nt < 4; ++nt)
            #pragma unroll
            for (int rg = 0; rg < 4; ++rg)
                mm = fmaxf(mm, sacc[nt][rg]);
        mm = fmaxf(mm, __shfl_xor(mm, 16));
        mm = fmaxf(mm, __shfl_xor(mm, 32));
        float pw[4][4];
        float sum = 0.f;
        #pragma unroll
        for (int nt = 0; nt < 4; ++nt)
            #pragma unroll
            for (int rg = 0; rg < 4; ++rg) {
                float e = exp2f(sacc[nt][rg] - mm);
                pw[nt][rg] = e;
                sum += e;
            }
        sum += __shfl_xor(sum, 16);
        sum += __shfl_xor(sum, 32);
        float inv = 1.0f / sum;
        unsigned pk[4][2];
        #pragma unroll
        for (int nt = 0; nt < 4; ++nt) {
            pk[nt][0] = pack2bf(pw[nt][0] * inv, pw[nt][1] * inv);
            pk[nt][1] = pack2bf(pw[nt][2] * inv, pw[nt][3] * inv);
        }
        // redistribute P to PV A-fragment layout
        u32x4 pa0, pa1;
        #pragma unroll
        for (int d = 0; d < 4; ++d) {
            int src = ((qg & 1) * 2 + (d >> 1)) * 16 + p;
            int lo0 = __shfl((int)pk[0][d & 1], src);
            int hi0 = __shfl((int)pk[1][d & 1], src);
            int lo1 = __shfl((int)pk[2][d & 1], src);
            int hi1 = __shfl((int)pk[3][d & 1], src);
            pa0[d] = (qg < 2) ? (unsigned)lo0 : (unsigned)hi0;
            pa1[d] = (qg < 2) ? (unsigned)lo1 : (unsigned)hi1;
        }
        bf16x8 a0 = __builtin_bit_cast(bf16x8, pa0);
        bf16x8 a1 = __builtin_bit_cast(bf16x8, pa1);
        // O = P @ v^T tiles
        f32x4 oacc[2] = {fzero, fzero};
        #pragma unroll
        for (int n2 = 0; n2 < 2; ++n2) {
            int vr = hd * 24 + n2 * 16 + p;
            vr = vr > 95 ? 95 : vr;           // clamp: cc>=24 lanes discarded anyway
            int rb = vr * 128, sw = (vr & 7) << 4;
            bf16x8 bv0 = *reinterpret_cast<const bf16x8*>(vtb + rb + ((qg * 16) ^ sw));
            bf16x8 bv1 = *reinterpret_cast<const bf16x8*>(vtb + rb + ((64 + qg * 16) ^ sw));
            oacc[n2] = MFMA16(a0, bv0, oacc[n2]);
            oacc[n2] = MFMA16(a1, bv1, oacc[n2]);
        }
        #pragma unroll
        for (int n2 = 0; n2 < 2; ++n2) {
            int cc = n2 * 16 + p;
            if (cc < 24) {
                #pragma unroll
                for (int rg = 0; rg < 4; ++rg)
                    *reinterpret_cast<unsigned short*>(xq + xq_addr(wv * 16 + qg * 4 + rg, hd * 24 + cc)) = cvt_bf(oacc[n2][rg]);
            }
        }
    }

    // ---------- phase 4: proj + bias + scatter (own rows only -> no barrier) ----------
    bf16x8 ofr[3];
    #pragma unroll
    for (int kt = 0; kt < 3; ++kt)
        ofr[kt] = *reinterpret_cast<const bf16x8*>(xq + xq_addr(wv * 16 + p, kt * 32 + qg * 8));
    const unsigned short* wpT = wsT + WQT_ELEMS;
    int obase = (((n_i * 4 + wv) * 64 + (m_i * 4 + qg)) * 128 + l_i * 4) * 96;
    #pragma unroll
    for (int nt = 0; nt < 6; ++nt) {
        f32x4 acc = fzero;
        #pragma unroll
        for (int kt = 0; kt < 3; ++kt) {
            bf16x8 bfr = *reinterpret_cast<const bf16x8*>(&wpT[(nt * 16 + p) * 96 + kt * 32 + qg * 8]);
            acc = MFMA16(ofr[kt], bfr, acc);
        }
        float bias = bproj[nt * 16 + p];
        #pragma unroll
        for (int rg = 0; rg < 4; ++rg)
            out[obase + rg * 96 + nt * 16 + p] = acc[rg] + bias;
    }
}

extern "C" void kernel_launch(void* const* d_in, const int* in_sizes, int n_in,
                              void* d_out, int out_size, void* d_ws, size_t ws_size,
                              hipStream_t stream) {
    const float* x     = (const float*)d_in[0];
    const float* wqkv  = (const float*)d_in[1];
    const float* wproj = (const float*)d_in[2];
    const float* bproj = (const float*)d_in[3];
    float* out = (float*)d_out;
    unsigned short* wsT = (unsigned short*)d_ws;

    wconv_kernel<<<dim3((WQT_ELEMS + WPT_ELEMS) / 256), dim3(256), 0, stream>>>(wqkv, wproj, wsT);
    winattn_kernel<<<dim3(4096), dim3(256), 0, stream>>>(x, wsT, bproj, out);
}

// Round 4
// 80.116 us; speedup vs baseline: 1.3453x; 1.3453x over previous
//
#include <hip/hip_runtime.h>
#include <hip/hip_bf16.h>

typedef __attribute__((ext_vector_type(8))) short bf16x8;
typedef __attribute__((ext_vector_type(4))) float f32x4;
typedef __attribute__((ext_vector_type(4))) unsigned short u16x4;
typedef __attribute__((ext_vector_type(4))) unsigned int u32x4;

#define MFMA16(a, b, c) __builtin_amdgcn_mfma_f32_16x16x32_bf16((a), (b), (c), 0, 0, 0)

#define WQT_ELEMS 27648   // 288*96
#define WPT_ELEMS 9216    // 96*96

__device__ __forceinline__ unsigned short cvt_bf(float f) {
    __hip_bfloat16 h = __float2bfloat16(f);   // native RNE conversion
    return *reinterpret_cast<unsigned short*>(&h);
}
__device__ __forceinline__ unsigned pack2bf(float a, float b) {
    return (unsigned)cvt_bf(a) | ((unsigned)cvt_bf(b) << 16);
}

// Transpose+convert weights; q-columns (j<96) pre-scaled by (1/sqrt(24))*log2(e)
__global__ void wconv_kernel(const float* __restrict__ wqkv,
                             const float* __restrict__ wproj,
                             unsigned short* __restrict__ wsT) {
    int o = blockIdx.x * 256 + threadIdx.x;
    if (o < WQT_ELEMS) {
        int j = o / 96, c = o % 96;
        float w = wqkv[c * 288 + j];
        if (j < 96) w *= 0.2944889313f;
        wsT[o] = cvt_bf(w);
    } else if (o < WQT_ELEMS + WPT_ELEMS) {
        int o2 = o - WQT_ELEMS;
        int j = o2 / 96, c = o2 % 96;
        wsT[o] = cvt_bf(wproj[c * 96 + j]);
    }
}

// Packed-swizzled address for the unified x/q/O buffer: logical (t in [0,64), c in [0,96)).
// 3 chunks of 32 cols; 2 token-rows per 128B line; XOR swizzle on bits 4-6.
__device__ __forceinline__ int xq_addr(int t, int c) {
    return ((c >> 5) << 12) + ((t >> 1) << 7)
         + ((((t & 1) << 6) + ((c & 31) << 1)) ^ (((t >> 1) & 7) << 4));
}

// One block per window. 256 threads = 4 waves. Wave wv owns token rows [16wv,16wv+16).
// LDS = 40960 B -> 4 blocks/CU.
__global__ __launch_bounds__(256, 4)
void winattn_kernel(const float* __restrict__ x,
                    const unsigned short* __restrict__ wsT,
                    const float* __restrict__ bproj,
                    float* __restrict__ out) {
    __shared__ __align__(16) char LDS[40960];
    char* xq  = LDS;              // 12288 B: x -> q -> O (packed-swizzled bf16)
    char* ksb = LDS + 12288;      // 16384 B: k, XOR-swizzled, head-padded K=32
    char* vtb = LDS + 28672;      // 12288 B: v^T [c][t], XOR-swizzled
    float* fbuf = reinterpret_cast<float*>(LDS + 12288);  // f32 proj out [64][stride 100] (reuses ks/vt)

    const int tid = threadIdx.x;
    const int lane = tid & 63;
    const int wv = tid >> 6;
    const int p  = lane & 15;
    const int qg = lane >> 4;

    const int iw  = blockIdx.x;
    const int l_i = iw & 31;
    const int m_i = (iw >> 5) & 15;
    const int n_i = iw >> 9;

    const f32x4 fzero = {0.f, 0.f, 0.f, 0.f};

    // QKV tile split: wv0: 0-4, wv1: 5-9, wv2: 10-13, wv3: 14-17
    const int ntile = (wv < 2) ? 5 : 4;
    const int tbase = (wv < 2) ? wv * 5 : 10 + (wv - 2) * 4;

    // ---------- phase 0: issue first B-tile prefetch (wsT independent of LDS) ----------
    bf16x8 bpre[3];
    #pragma unroll
    for (int kt = 0; kt < 3; ++kt)
        bpre[kt] = *reinterpret_cast<const bf16x8*>(&wsT[(tbase * 16 + p) * 96 + kt * 32 + qg * 8]);

    // ---------- phase 1: stage x window -> LDS (bf16, packed layout) ----------
    #pragma unroll
    for (int it = 0; it < 6; ++it) {
        int slot = tid + it * 256;            // 64 tokens * 24 float4 slots
        int t = slot / 24, cq = slot % 24;
        int td = t >> 4, th = (t >> 2) & 3, tw = t & 3;
        int off = (((n_i * 4 + td) * 64 + (m_i * 4 + th)) * 128 + (l_i * 4 + tw)) * 96 + cq * 4;
        float4 v4 = *reinterpret_cast<const float4*>(x + off);
        u16x4 h;
        h[0] = cvt_bf(v4.x); h[1] = cvt_bf(v4.y); h[2] = cvt_bf(v4.z); h[3] = cvt_bf(v4.w);
        *reinterpret_cast<u16x4*>(xq + xq_addr(t, cq * 4)) = h;
    }
    // zero k head-pads (kk 24..31 per head, swizzled addr)
    {
        int t = tid >> 2, hd = tid & 3;
        bf16x8 z = {0, 0, 0, 0, 0, 0, 0, 0};
        int cb = hd * 64 + 48;
        *reinterpret_cast<bf16x8*>(ksb + t * 256 + (cb ^ ((t & 7) << 4))) = z;
    }
    __syncthreads();

    // ---------- phase 2: QKV GEMM  qkv[64][288] = x[64][96] @ wq[96][288] ----------
    bf16x8 afr[4][3];
    #pragma unroll
    for (int mt = 0; mt < 4; ++mt)
        #pragma unroll
        for (int kt = 0; kt < 3; ++kt)
            afr[mt][kt] = *reinterpret_cast<const bf16x8*>(xq + xq_addr(mt * 16 + p, kt * 32 + qg * 8));
    __syncthreads();   // xq fully register-hoisted; q may now overwrite it

    #pragma unroll
    for (int i = 0; i < 5; ++i) {
        if (i >= ntile) break;                // wave-uniform
        int nt = tbase + i;
        bf16x8 bcur[3] = {bpre[0], bpre[1], bpre[2]};
        if (i + 1 < ntile) {                  // lookahead prefetch
            #pragma unroll
            for (int kt = 0; kt < 3; ++kt)
                bpre[kt] = *reinterpret_cast<const bf16x8*>(&wsT[((nt + 1) * 16 + p) * 96 + kt * 32 + qg * 8]);
        }
        f32x4 acc[4] = {fzero, fzero, fzero, fzero};
        #pragma unroll
        for (int kt = 0; kt < 3; ++kt)
            #pragma unroll
            for (int mt = 0; mt < 4; ++mt)
                acc[mt] = MFMA16(afr[mt][kt], bcur[kt], acc[mt]);
        int jcol = nt * 16 + p;               // D: col = lane&15, row = qg*4+rg (+16mt)
        if (jcol < 96) {                      // q (pre-scaled via weights)
            #pragma unroll
            for (int mt = 0; mt < 4; ++mt)
                #pragma unroll
                for (int rg = 0; rg < 4; ++rg)
                    *reinterpret_cast<unsigned short*>(xq + xq_addr(mt * 16 + qg * 4 + rg, jcol)) = cvt_bf(acc[mt][rg]);
        } else if (jcol < 192) {              // k, swizzled
            int jk = jcol - 96;
            int hd = jk / 24, kk = jk % 24;
            int cb = hd * 64 + kk * 2;
            #pragma unroll
            for (int mt = 0; mt < 4; ++mt)
                #pragma unroll
                for (int rg = 0; rg < 4; ++rg) {
                    int t = mt * 16 + qg * 4 + rg;
                    *reinterpret_cast<unsigned short*>(ksb + t * 256 + (cb ^ ((t & 7) << 4))) = cvt_bf(acc[mt][rg]);
                }
        } else {                              // v^T, swizzled
            int jv = jcol - 192;
            int hd = jv / 24, cc = jv % 24;
            int vr = hd * 24 + cc;
            int rb = vr * 128, sw = (vr & 7) << 4;
            #pragma unroll
            for (int mt = 0; mt < 4; ++mt)
                #pragma unroll
                for (int rg = 0; rg < 4; ++rg) {
                    int u = mt * 16 + qg * 4 + rg;
                    *reinterpret_cast<unsigned short*>(vtb + rb + ((u * 2) ^ sw)) = cvt_bf(acc[mt][rg]);
                }
        }
    }
    __syncthreads();

    // ---------- phase 3: attention, swapped QK^T -> register softmax ----------
    #pragma unroll 1
    for (int hd = 0; hd < 4; ++hd) {
        // S^T = mfma(K, Q): D[col=q-token(p), row=k-token(qg*4+rg)+16nt]
        bf16x8 aqh = *reinterpret_cast<const bf16x8*>(xq + xq_addr(wv * 16 + p, hd * 24 + qg * 8));
        f32x4 sacc[4];
        #pragma unroll
        for (int nt = 0; nt < 4; ++nt) {
            int t = nt * 16 + p;
            bf16x8 ak = *reinterpret_cast<const bf16x8*>(ksb + t * 256 + ((hd * 64 + qg * 16) ^ ((t & 7) << 4)));
            sacc[nt] = MFMA16(ak, aqh, fzero);
        }
        // lane (p,qg) holds S[k = 16nt+4qg+rg][q = wv*16+p] (already *scale*log2e)
        float mm = sacc[0][0];
        #pragma unroll
        for (int nt = 0; nt < 4; ++nt)
            #pragma unroll
            for (int rg = 0; rg < 4; ++rg)
                mm = fmaxf(mm, sacc[nt][rg]);
        mm = fmaxf(mm, __shfl_xor(mm, 16));
        mm = fmaxf(mm, __shfl_xor(mm, 32));
        float pw[4][4];
        float sum = 0.f;
        #pragma unroll
        for (int nt = 0; nt < 4; ++nt)
            #pragma unroll
            for (int rg = 0; rg < 4; ++rg) {
                float e = exp2f(sacc[nt][rg] - mm);
                pw[nt][rg] = e;
                sum += e;
            }
        sum += __shfl_xor(sum, 16);
        sum += __shfl_xor(sum, 32);
        float inv = 1.0f / sum;
        unsigned pk[4][2];
        #pragma unroll
        for (int nt = 0; nt < 4; ++nt) {
            pk[nt][0] = pack2bf(pw[nt][0] * inv, pw[nt][1] * inv);
            pk[nt][1] = pack2bf(pw[nt][2] * inv, pw[nt][3] * inv);
        }
        // redistribute P to PV A-fragment layout
        u32x4 pa0, pa1;
        #pragma unroll
        for (int d = 0; d < 4; ++d) {
            int src = ((qg & 1) * 2 + (d >> 1)) * 16 + p;
            int lo0 = __shfl((int)pk[0][d & 1], src);
            int hi0 = __shfl((int)pk[1][d & 1], src);
            int lo1 = __shfl((int)pk[2][d & 1], src);
            int hi1 = __shfl((int)pk[3][d & 1], src);
            pa0[d] = (qg < 2) ? (unsigned)lo0 : (unsigned)hi0;
            pa1[d] = (qg < 2) ? (unsigned)lo1 : (unsigned)hi1;
        }
        bf16x8 a0 = __builtin_bit_cast(bf16x8, pa0);
        bf16x8 a1 = __builtin_bit_cast(bf16x8, pa1);
        // O = P @ v^T tiles
        f32x4 oacc[2] = {fzero, fzero};
        #pragma unroll
        for (int n2 = 0; n2 < 2; ++n2) {
            int vr = hd * 24 + n2 * 16 + p;
            vr = vr > 95 ? 95 : vr;           // clamp: cc>=24 lanes discarded anyway
            int rb = vr * 128, sw = (vr & 7) << 4;
            bf16x8 bv0 = *reinterpret_cast<const bf16x8*>(vtb + rb + ((qg * 16) ^ sw));
            bf16x8 bv1 = *reinterpret_cast<const bf16x8*>(vtb + rb + ((64 + qg * 16) ^ sw));
            oacc[n2] = MFMA16(a0, bv0, oacc[n2]);
            oacc[n2] = MFMA16(a1, bv1, oacc[n2]);
        }
        #pragma unroll
        for (int n2 = 0; n2 < 2; ++n2) {
            int cc = n2 * 16 + p;
            if (cc < 24) {
                #pragma unroll
                for (int rg = 0; rg < 4; ++rg)
                    *reinterpret_cast<unsigned short*>(xq + xq_addr(wv * 16 + qg * 4 + rg, hd * 24 + cc)) = cvt_bf(oacc[n2][rg]);
            }
        }
    }

    // ---------- phase 4: proj + bias -> f32 LDS (own rows only) ----------
    bf16x8 ofr[3];
    #pragma unroll
    for (int kt = 0; kt < 3; ++kt)
        ofr[kt] = *reinterpret_cast<const bf16x8*>(xq + xq_addr(wv * 16 + p, kt * 32 + qg * 8));
    __syncthreads();   // all waves done with ksb/vtb (phase 3) before fbuf overlays them

    const unsigned short* wpT = wsT + WQT_ELEMS;
    bf16x8 wpre[3];
    #pragma unroll
    for (int kt = 0; kt < 3; ++kt)
        wpre[kt] = *reinterpret_cast<const bf16x8*>(&wpT[p * 96 + kt * 32 + qg * 8]);
    #pragma unroll
    for (int nt = 0; nt < 6; ++nt) {
        bf16x8 wcur[3] = {wpre[0], wpre[1], wpre[2]};
        if (nt < 5) {
            #pragma unroll
            for (int kt = 0; kt < 3; ++kt)
                wpre[kt] = *reinterpret_cast<const bf16x8*>(&wpT[((nt + 1) * 16 + p) * 96 + kt * 32 + qg * 8]);
        }
        f32x4 acc = fzero;
        #pragma unroll
        for (int kt = 0; kt < 3; ++kt)
            acc = MFMA16(ofr[kt], wcur[kt], acc);
        float bias = bproj[nt * 16 + p];
        #pragma unroll
        for (int rg = 0; rg < 4; ++rg)
            fbuf[(wv * 16 + qg * 4 + rg) * 100 + nt * 16 + p] = acc[rg] + bias;
    }
    __syncthreads();

    // ---------- phase 5: cooperative fully-coalesced f32 store (mirrors phase 1) ----------
    #pragma unroll
    for (int it = 0; it < 6; ++it) {
        int slot = tid + it * 256;
        int t = slot / 24, cq = slot % 24;
        int td = t >> 4, th = (t >> 2) & 3, tw = t & 3;
        int off = (((n_i * 4 + td) * 64 + (m_i * 4 + th)) * 128 + (l_i * 4 + tw)) * 96 + cq * 4;
        float4 v4 = *reinterpret_cast<const float4*>(fbuf + t * 100 + cq * 4);
        *reinterpret_cast<float4*>(out + off) = v4;
    }
}

extern "C" void kernel_launch(void* const* d_in, const int* in_sizes, int n_in,
                              void* d_out, int out_size, void* d_ws, size_t ws_size,
                              hipStream_t stream) {
    const float* x     = (const float*)d_in[0];
    const float* wqkv  = (const float*)d_in[1];
    const float* wproj = (const float*)d_in[2];
    const float* bproj = (const float*)d_in[3];
    float* out = (float*)d_out;
    unsigned short* wsT = (unsigned short*)d_ws;

    wconv_kernel<<<dim3((WQT_ELEMS + WPT_ELEMS) / 256), dim3(256), 0, stream>>>(wqkv, wproj, wsT);
    winattn_kernel<<<dim3(4096), dim3(256), 0, stream>>>(x, wsT, bproj, out);
}